// Round 3
// baseline (634.357 us; speedup 1.0000x reference)
//
#include <hip/hip_runtime.h>
#include <stdint.h>

#define T_LEN 2048
#define KAUG  1056
#define M_TOT 65536
#define TILE_U16 135168   // 33 steps * 4096 u16 per mblk tile

typedef __attribute__((ext_vector_type(8))) short short8;
typedef __attribute__((ext_vector_type(4))) float f32x4;
typedef unsigned int u32;
typedef unsigned short u16;

__device__ __forceinline__ u16 bf16_rn(float f){
  u32 u = __builtin_bit_cast(u32, f);
  u32 r = u + 0x7fffu + ((u >> 16) & 1u);
  return (u16)(r >> 16);
}
__device__ __forceinline__ u32 pack_rn(float lo, float hi){
  return (u32)bf16_rn(lo) | ((u32)bf16_rn(hi) << 16);
}
__device__ __forceinline__ u32 pack_trunc(float lo, float hi){
  u32 a = __builtin_bit_cast(u32, lo);
  u32 b = __builtin_bit_cast(u32, hi);
  return (a >> 16) | (b & 0xffff0000u);
}
__device__ __forceinline__ void lds_load16(const void* g, void* l){
  __builtin_amdgcn_global_load_lds(
      (const __attribute__((address_space(1))) u32*)g,
      (__attribute__((address_space(3))) u32*)l, 16, 0, 0);
}

// ---------- k0a: Bt[n][k] = concat(W_enc,W_att)[k][n] as bf16 (512 x 1056) ----------
__global__ void k_build_bt(const float* __restrict__ W_enc,
                           const float* __restrict__ W_att,
                           u16* __restrict__ Bt){
  __shared__ float tile[32][33];
  int k0 = blockIdx.x * 32, n0 = blockIdx.y * 32;
  int tx = threadIdx.x & 31, ty = threadIdx.x >> 5;
  #pragma unroll
  for (int i = 0; i < 4; i++){
    int k = k0 + i*8 + ty;
    int n = n0 + tx;
    float v = (k < 1024) ? W_enc[k*512 + n] : W_att[(k-1024)*512 + n];
    tile[i*8+ty][tx] = v;
  }
  __syncthreads();
  #pragma unroll
  for (int i = 0; i < 4; i++){
    int n = n0 + i*8 + ty;
    int k = k0 + tx;
    Bt[(size_t)n*KAUG + k] = bf16_rn(tile[tx][i*8+ty]);
  }
}

// ---------- k0b: bias[b][n] = b_enc[n] + dec_z[b] @ W_dec[:,n]  (fp32, split-K) ----------
__global__ void k_bias(const float* __restrict__ dec_z,
                       const float* __restrict__ W_dec,
                       const float* __restrict__ b_enc,
                       float* __restrict__ bias){
  __shared__ float red[4][64];
  int b = blockIdx.y, n0 = blockIdx.x * 64;          // grid (8,32)
  int nl = threadIdx.x & 63, ks = threadIdx.x >> 6;  // 4 k-slices of 256
  int n = n0 + nl;
  const float* dz = dec_z + b*1024;
  float s = 0.f;
  #pragma unroll 4
  for (int k = ks*256; k < ks*256 + 256; k++) s += dz[k] * W_dec[k*512 + n];
  red[ks][nl] = s;
  __syncthreads();
  if (threadIdx.x < 64){
    int nn = n0 + threadIdx.x;
    bias[b*512 + nn] = b_enc[nn] + red[0][threadIdx.x] + red[1][threadIdx.x]
                     + red[2][threadIdx.x] + red[3][threadIdx.x];
  }
}

// ---------- k_pack: Apack[mblk][t][r][k] bf16 tile-contiguous from enc fp32 ----------
// Per K-step the GEMM's A-tile becomes ONE contiguous 8 KB block -> dense glds.
__global__ void k_pack(const float* __restrict__ enc, u16* __restrict__ Apack){
  int e = blockIdx.x*256 + threadIdx.x;   // 65536 rows * 128 chunks
  int row   = e >> 7;
  int chunk = e & 127;                    // 8 k-values per chunk
  const float* src = enc + (size_t)row*1024 + chunk*8;
  f32x4 a = *(const f32x4*)src;
  f32x4 b = *(const f32x4*)(src + 4);
  union { u32 u[4]; short8 v; } cv;
  cv.u[0] = pack_rn(a.x, a.y);
  cv.u[1] = pack_rn(a.z, a.w);
  cv.u[2] = pack_rn(b.x, b.y);
  cv.u[3] = pack_rn(b.z, b.w);
  int mblk = row >> 7, t = chunk >> 2, kin = (chunk & 3)*8;
  u16* d = Apack + (size_t)mblk*TILE_U16 + t*4096 + (row & 127)*32 + kin;
  *(short8*)d = cv.v;
}

// ---------- k_conv_p: conv1d(att_prev) -> bf16 directly into Apack kstep=32 ----------
__global__ void k_conv_p(const float* __restrict__ att_prev,
                         const float* __restrict__ conv_w,
                         u16* __restrict__ Apack){
  int idx = blockIdx.x*256 + threadIdx.x;     // 65536*32 total
  int c = idx & 31;
  int bt = idx >> 5;
  int b = bt >> 11, t = bt & 2047;
  const float* ap = att_prev + b*2048;
  const float* cw = conv_w + c*31;
  float s = 0.f;
  #pragma unroll
  for (int j = 0; j < 31; j++){
    int tt = t + j - 15;
    float a = (tt >= 0 && tt < 2048) ? ap[tt] : 0.f;
    s += cw[j] * a;
  }
  int mblk = bt >> 7;
  Apack[(size_t)mblk*TILE_U16 + 32*4096 + (bt & 127)*32 + c] = bf16_rn(s);
}

// ---------- GEMM (packed A) + fused tanh/Wg epilogue -> ePart[nblk][65536] ----------
// A: bf16 tile-contiguous Apack; staged via global_load_lds (2 contiguous 1KB
// issues/wave per step) into a depth-3 LDS ring (3 x 8 KB). STAGE(t+2) issued
// AFTER barrier(t) -> safe to overwrite buf[(t-1)%3] (all waves finished
// COMPUTE(t-1) at that barrier). Counted vmcnt(6): steady queue is
// [g(t)x2, B(t)x4, g(t+1)x2, B(t+1)x4]; wait-6 drains g(t),B(t), keeps 6 newest
// in flight (counted-from-newest => older compiler-hoisted loads are harmless).
// glds load->use distance = 2 iterations. B = Bt (L2-resident) direct to regs,
// prefetched 1 step ahead. No A regs, no pack on critical path ->
// ~60 VGPR + 64 acc => launch_bounds(256,4) = 4 blocks/CU (16 waves).
// Fragment ds_read_b128: slot = 4*m + kg is a bijection onto the 64 16B-slots
// of each 1KB row-group -> uniform bank load, no swizzle needed.
__launch_bounds__(256, 4)
__global__ void k_gemm_energy_p(const u16* __restrict__ Apack,
                                const u16* __restrict__ Bt,
                                const float* __restrict__ bias,
                                const float* __restrict__ Wg,
                                float* __restrict__ ePart){
  __shared__ __align__(16) u16 Ash[3][4096];   // 3 x 8 KB
  __shared__ float eRed[2][128];

  const int tid  = threadIdx.x;
  const int lane = tid & 63;
  const int wid  = tid >> 6;
  const int wave_m = wid >> 1, wave_n = wid & 1;
  // XCD-sibling swizzle: 4 nblk-siblings of each mblk -> same XCD (L2/L3 share)
  const int bidx = blockIdx.x;            // 0..2047
  const int xcd  = bidx & 7;
  const int s_sq = bidx >> 3;
  const int nblk = s_sq & 3;
  const int mblk = ((s_sq >> 2) << 3) + xcd;
  const int row0 = mblk << 7;
  const int b    = mblk >> 4;

  f32x4 acc[4][4];
  #pragma unroll
  for (int i = 0; i < 4; i++)
    #pragma unroll
    for (int j = 0; j < 4; j++) acc[i][j] = (f32x4)(0.f);

  const int fr_m = lane & 15;
  const int kg   = lane >> 4;

  const u16* Atile = Apack + (size_t)mblk*TILE_U16;
  const u16* asrc  = Atile + (wid*2)*512 + lane*8;   // per-lane glds source base
  const u16* BtN   = Bt + (size_t)(nblk*128)*KAUG;

  // B row base pointers (per-call offset t*32 u16 = t*64 B fits imm offset)
  const u16* bptr0 = BtN + (size_t)(wave_n*64 +  0 + fr_m)*KAUG + kg*8;
  const u16* bptr1 = BtN + (size_t)(wave_n*64 + 16 + fr_m)*KAUG + kg*8;
  const u16* bptr2 = BtN + (size_t)(wave_n*64 + 32 + fr_m)*KAUG + kg*8;
  const u16* bptr3 = BtN + (size_t)(wave_n*64 + 48 + fr_m)*KAUG + kg*8;

  int aroff[4];
  #pragma unroll
  for (int mi = 0; mi < 4; mi++){
    int m = wave_m*64 + mi*16 + fr_m;
    aroff[mi] = m*32 + kg*8;
  }

  auto STAGE = [&](int t, int bufi){
    const u16* s0 = asrc + t*4096;
    lds_load16(s0,       &Ash[bufi][(wid*2 + 0)*512]);
    lds_load16(s0 + 512, &Ash[bufi][(wid*2 + 1)*512]);
  };
  auto LOADBF = [&](int t, short8* bf){
    bf[0] = *(const short8*)(bptr0 + t*32);
    bf[1] = *(const short8*)(bptr1 + t*32);
    bf[2] = *(const short8*)(bptr2 + t*32);
    bf[3] = *(const short8*)(bptr3 + t*32);
  };
  auto COMPUTE = [&](int bufi, const short8* bf){
    #pragma unroll
    for (int mi = 0; mi < 4; mi++){
      short8 af = *(const short8*)&Ash[bufi][aroff[mi]];
      #pragma unroll
      for (int ni = 0; ni < 4; ni++)
        acc[mi][ni] = __builtin_amdgcn_mfma_f32_16x16x32_bf16(af, bf[ni], acc[mi][ni], 0, 0, 0);
    }
  };

  short8 bfA[4], bfB[4];
  STAGE(0, 0);
  LOADBF(0, bfA);
  STAGE(1, 1);
  // queue: [g0 x2, B0 x4, g1 x2]

  int bE = 0;
  #pragma unroll 1
  for (int i = 0; i < 16; i++){
    int t  = 2*i;
    int bO = (bE == 2) ? 0 : bE + 1;
    int sE = (bO == 2) ? 0 : bO + 1;   // (t+2)%3
    int sO = bE;                       // (t+3)%3
    // ---- even step t ----
    LOADBF(t+1, bfB);
    asm volatile("s_waitcnt vmcnt(6)" ::: "memory");   // g(t),B(t) done
    __builtin_amdgcn_s_barrier();
    asm volatile("" ::: "memory");
    if (t < 31) STAGE(t+2, sE);
    COMPUTE(bE, bfA);
    // ---- odd step t+1 ----
    LOADBF(t+2, bfA);                                  // t+2 <= 32
    asm volatile("s_waitcnt vmcnt(6)" ::: "memory");   // g(t+1),B(t+1) done
    __builtin_amdgcn_s_barrier();
    asm volatile("" ::: "memory");
    if (t+1 < 31) STAGE(t+3, sO);
    COMPUTE(bO, bfB);
    bE = sE;
  }
  // ---- step 32 ----
  asm volatile("s_waitcnt vmcnt(0)" ::: "memory");
  __builtin_amdgcn_s_barrier();
  asm volatile("" ::: "memory");
  COMPUTE(bE, bfA);   // bE == 32%3 == 2

  // epilogue: e_partial[row] = sum_n Wg[n] * tanh(acc + bias[b][n]) over this block's 128 n
  float wg[4], bs[4];
  #pragma unroll
  for (int ni = 0; ni < 4; ni++){
    int ng = nblk*128 + wave_n*64 + ni*16 + fr_m;
    wg[ni] = Wg[ng];
    bs[ni] = bias[b*512 + ng];
  }
  #pragma unroll
  for (int mi = 0; mi < 4; mi++){
    #pragma unroll
    for (int reg = 0; reg < 4; reg++){
      float s = 0.f;
      #pragma unroll
      for (int ni = 0; ni < 4; ni++){
        float v  = acc[mi][ni][reg] + bs[ni];
        float e2 = __expf(2.f * v);
        float th = 1.f - 2.f/(e2 + 1.f);   // tanh(v); saturates correctly at +/-1
        s += wg[ni] * th;
      }
      s += __shfl_xor(s, 1);
      s += __shfl_xor(s, 2);
      s += __shfl_xor(s, 4);
      s += __shfl_xor(s, 8);
      if (fr_m == 0){
        int rowl = wave_m*64 + mi*16 + kg*4 + reg;
        eRed[wave_n][rowl] = s;
      }
    }
  }
  __syncthreads();
  if (tid < 128)
    ePart[(size_t)nblk*M_TOT + row0 + tid] = eRed[0][tid] + eRed[1][tid];
}

// ================= fallback path (round-2 kernels) if workspace too small ===========
__global__ void k_conv_f(const float* __restrict__ att_prev,
                         const float* __restrict__ conv_w,
                         float* __restrict__ attT){
  int idx = blockIdx.x*256 + threadIdx.x;
  int c = idx & 31;
  int bt = idx >> 5;
  int b = bt >> 11, t = bt & 2047;
  const float* ap = att_prev + b*2048;
  const float* cw = conv_w + c*31;
  float s = 0.f;
  #pragma unroll
  for (int j = 0; j < 31; j++){
    int tt = t + j - 15;
    float a = (tt >= 0 && tt < 2048) ? ap[tt] : 0.f;
    s += cw[j] * a;
  }
  attT[(size_t)bt*32 + c] = s;
}

__launch_bounds__(256, 3)
__global__ void k_gemm_energy_f(const float* __restrict__ enc,
                                const float* __restrict__ attT,
                                const u16* __restrict__ Bt,
                                const float* __restrict__ bias,
                                const float* __restrict__ Wg,
                                float* __restrict__ ePart){
  __shared__ __align__(16) u16 Ash[2][128*32];
  __shared__ float eRed[2][128];
  const int tid  = threadIdx.x;
  const int lane = tid & 63;
  const int wid  = tid >> 6;
  const int wave_m = wid >> 1, wave_n = wid & 1;
  const int bidx = blockIdx.x;
  const int xcd  = bidx & 7;
  const int s_sq = bidx >> 3;
  const int nblk = s_sq & 3;
  const int mblk = ((s_sq >> 2) << 3) + xcd;
  const int row0 = mblk << 7;
  const int b    = mblk >> 4;
  f32x4 acc[4][4];
  #pragma unroll
  for (int i = 0; i < 4; i++)
    #pragma unroll
    for (int j = 0; j < 4; j++) acc[i][j] = (f32x4)(0.f);
  const int srow = lane >> 2;
  const int sc   = lane & 3;
  const int fr_m = lane & 15;
  const int kg   = lane >> 4;
  const u16* BtN = Bt + (size_t)(nblk*128)*KAUG;
  int r0q[2], ldsoff[2];
  #pragma unroll
  for (int q = 0; q < 2; q++){
    int r = wid*32 + q*16 + srow;
    r0q[q] = r;
    ldsoff[q] = r*32 + (sc ^ ((r >> 1) & 3))*8;
  }
  int aroff[4];
  #pragma unroll
  for (int mi = 0; mi < 4; mi++){
    int m = wave_m*64 + mi*16 + fr_m;
    aroff[mi] = m*32 + (kg ^ ((m >> 1) & 3))*8;
  }
  int bnrow[4];
  #pragma unroll
  for (int ni = 0; ni < 4; ni++)
    bnrow[ni] = wave_n*64 + ni*16 + fr_m;
  auto LOADA = [&](int t, f32x4* ra){
    const float* base; size_t rstr;
    if (t < 32){ base = enc + (size_t)row0*1024 + t*32; rstr = 1024; }
    else       { base = attT + (size_t)row0*32;         rstr = 32;  }
    #pragma unroll
    for (int q = 0; q < 2; q++){
      const float* p = base + (size_t)r0q[q]*rstr + sc*8;
      ra[q*2+0] = *(const f32x4*)(p);
      ra[q*2+1] = *(const f32x4*)(p + 4);
    }
  };
  auto LOADBF = [&](int t, short8* bf){
    #pragma unroll
    for (int ni = 0; ni < 4; ni++)
      bf[ni] = *(const short8*)(BtN + (size_t)bnrow[ni]*KAUG + t*32 + kg*8);
  };
  auto WRITEA = [&](const f32x4* ra, int bi){
    #pragma unroll
    for (int q = 0; q < 2; q++){
      f32x4 lo = ra[q*2+0], hi = ra[q*2+1];
      union { u32 u[4]; short8 v; } cv;
      cv.u[0] = pack_trunc(lo.x, lo.y);
      cv.u[1] = pack_trunc(lo.z, lo.w);
      cv.u[2] = pack_trunc(hi.x, hi.y);
      cv.u[3] = pack_trunc(hi.z, hi.w);
      *(short8*)&Ash[bi][ldsoff[q]] = cv.v;
    }
  };
  auto COMPUTE = [&](int bi, const short8* bf){
    const u16* Ab = &Ash[bi][0];
    #pragma unroll
    for (int mi = 0; mi < 4; mi++){
      short8 af = *(const short8*)(Ab + aroff[mi]);
      #pragma unroll
      for (int ni = 0; ni < 4; ni++)
        acc[mi][ni] = __builtin_amdgcn_mfma_f32_16x16x32_bf16(af, bf[ni], acc[mi][ni], 0, 0, 0);
    }
  };
  f32x4 raA[4], raB[4];
  short8 bfA[4], bfB[4];
  LOADA(0, raA); LOADBF(0, bfA);
  #pragma unroll 1
  for (int i = 0; i < 16; i++){
    int kk = 2*i;
    LOADA(kk+1, raB); LOADBF(kk+1, bfB);
    WRITEA(raA, 0);
    asm volatile("s_waitcnt lgkmcnt(0)" ::: "memory");
    __builtin_amdgcn_s_barrier();
    asm volatile("" ::: "memory");
    COMPUTE(0, bfA);
    LOADA(kk+2, raA); LOADBF(kk+2, bfA);
    WRITEA(raB, 1);
    asm volatile("s_waitcnt lgkmcnt(0)" ::: "memory");
    __builtin_amdgcn_s_barrier();
    asm volatile("" ::: "memory");
    COMPUTE(1, bfB);
  }
  WRITEA(raA, 0);
  asm volatile("s_waitcnt lgkmcnt(0)" ::: "memory");
  __builtin_amdgcn_s_barrier();
  asm volatile("" ::: "memory");
  COMPUTE(0, bfA);
  float wg[4], bs[4];
  #pragma unroll
  for (int ni = 0; ni < 4; ni++){
    int ng = nblk*128 + wave_n*64 + ni*16 + fr_m;
    wg[ni] = Wg[ng];
    bs[ni] = bias[b*512 + ng];
  }
  #pragma unroll
  for (int mi = 0; mi < 4; mi++){
    #pragma unroll
    for (int reg = 0; reg < 4; reg++){
      float s = 0.f;
      #pragma unroll
      for (int ni = 0; ni < 4; ni++){
        float v  = acc[mi][ni][reg] + bs[ni];
        float e2 = __expf(2.f * v);
        float th = 1.f - 2.f/(e2 + 1.f);
        s += wg[ni] * th;
      }
      s += __shfl_xor(s, 1);
      s += __shfl_xor(s, 2);
      s += __shfl_xor(s, 4);
      s += __shfl_xor(s, 8);
      if (fr_m == 0){
        int rowl = wave_m*64 + mi*16 + kg*4 + reg;
        eRed[wave_n][rowl] = s;
      }
    }
  }
  __syncthreads();
  if (tid < 128)
    ePart[(size_t)nblk*M_TOT + row0 + tid] = eRed[0][tid] + eRed[1][tid];
}
// ================= end fallback =====================================================

// ---------- masked softmax over T per batch (SCALING=2; b_g cancels) ----------
__global__ void k_softmax(const float* __restrict__ ePart,
                          const int* __restrict__ lens,
                          float* __restrict__ wout){
  int b = blockIdx.x, tid = threadIdx.x;
  int lane = tid & 63, wid = tid >> 6;
  int len = lens[b];
  __shared__ float red[4];
  float x[8]; float m = -3.0e38f;
  #pragma unroll
  for (int i = 0; i < 8; i++){
    int t = tid + i*256;
    int idx = b*2048 + t;
    float e = ePart[idx] + ePart[M_TOT + idx] + ePart[2*M_TOT + idx] + ePart[3*M_TOT + idx];
    float xx = (t < len) ? 2.0f*e : -3.0e38f;
    x[i] = xx; m = fmaxf(m, xx);
  }
  #pragma unroll
  for (int o = 1; o < 64; o <<= 1) m = fmaxf(m, __shfl_xor(m, o));
  if (lane == 0) red[wid] = m;
  __syncthreads();
  m = fmaxf(fmaxf(red[0], red[1]), fmaxf(red[2], red[3]));
  float s = 0.f;
  #pragma unroll
  for (int i = 0; i < 8; i++){
    float ex = (x[i] > -1.0e38f) ? __expf(x[i] - m) : 0.f;
    x[i] = ex; s += ex;
  }
  #pragma unroll
  for (int o = 1; o < 64; o <<= 1) s += __shfl_xor(s, o);
  __syncthreads();
  if (lane == 0) red[wid] = s;
  __syncthreads();
  s = red[0] + red[1] + red[2] + red[3];
  float inv = 1.0f / s;
  #pragma unroll
  for (int i = 0; i < 8; i++){
    int t = tid + i*256;
    wout[b*2048 + t] = x[i]*inv;
  }
}

// ---------- context: cPart[tc][b][d] = sum_{t in tc} w[b,t]*enc[b,t,d] ----------
__global__ void k_ctx_partial(const float* __restrict__ enc,
                              const float* __restrict__ w,
                              float* __restrict__ cPart){
  int dc = blockIdx.x, tc = blockIdx.y, b = blockIdx.z;
  int d = dc*256 + threadIdx.x;
  const float* ep = enc + ((size_t)(b*2048 + tc*256))*1024 + d;
  const float* wp = w + b*2048 + tc*256;
  float s0 = 0, s1 = 0, s2 = 0, s3 = 0;
  #pragma unroll 2
  for (int t = 0; t < 256; t += 4){
    s0 += wp[t+0] * ep[(size_t)(t+0)*1024];
    s1 += wp[t+1] * ep[(size_t)(t+1)*1024];
    s2 += wp[t+2] * ep[(size_t)(t+2)*1024];
    s3 += wp[t+3] * ep[(size_t)(t+3)*1024];
  }
  cPart[((size_t)tc*32 + b)*1024 + d] = (s0 + s1) + (s2 + s3);
}

__global__ void k_ctx_reduce(const float* __restrict__ cPart, float* __restrict__ cOut){
  int idx = blockIdx.x*256 + threadIdx.x;   // 32768
  float s = 0.f;
  #pragma unroll
  for (int tc = 0; tc < 8; tc++) s += cPart[tc*32768 + idx];
  cOut[idx] = s;
}

extern "C" void kernel_launch(void* const* d_in, const int* in_sizes, int n_in,
                              void* d_out, int out_size, void* d_ws, size_t ws_size,
                              hipStream_t stream){
  (void)in_sizes; (void)n_in; (void)out_size;
  const float* enc    = (const float*)d_in[0];
  const int*   lens   = (const int*)  d_in[1];
  const float* dec_z  = (const float*)d_in[2];
  const float* att_p  = (const float*)d_in[3];
  const float* W_enc  = (const float*)d_in[4];
  const float* b_enc  = (const float*)d_in[5];
  const float* W_dec  = (const float*)d_in[6];
  const float* W_att  = (const float*)d_in[7];
  const float* conv_w = (const float*)d_in[8];
  const float* W_g    = (const float*)d_in[9];
  // d_in[10] = b_g: cancels inside softmax, unused.

  float* c_out = (float*)d_out;          // (32,1024)
  float* w_out = c_out + 32*1024;        // (32,2048)

  char* ws = (char*)d_ws;

  if (ws_size >= 141656064ull){
    // primary layout: Bt | bias | ePart | cPart | Apack
    u16*   Bt    = (u16*)  (ws);                       // 1,081,344 B
    float* bias  = (float*)(ws + 1081344);             // 65,536 B
    float* ePart = (float*)(ws + 1146880);             // 1,048,576 B
    float* cPart = (float*)(ws + 2195456);             // 1,048,576 B
    u16*   Apack = (u16*)  (ws + 3244032);             // 138,412,032 B

    hipLaunchKernelGGL(k_build_bt,      dim3(33,16),  dim3(256), 0, stream, W_enc, W_att, Bt);
    hipLaunchKernelGGL(k_bias,          dim3(8,32),   dim3(256), 0, stream, dec_z, W_dec, b_enc, bias);
    hipLaunchKernelGGL(k_pack,          dim3(32768),  dim3(256), 0, stream, enc, Apack);
    hipLaunchKernelGGL(k_conv_p,        dim3(8192),   dim3(256), 0, stream, att_p, conv_w, Apack);
    hipLaunchKernelGGL(k_gemm_energy_p, dim3(2048),   dim3(256), 0, stream, Apack, Bt, bias, W_g, ePart);
    hipLaunchKernelGGL(k_softmax,       dim3(32),     dim3(256), 0, stream, ePart, lens, w_out);
    hipLaunchKernelGGL(k_ctx_partial,   dim3(4,8,32), dim3(256), 0, stream, enc, w_out, cPart);
    hipLaunchKernelGGL(k_ctx_reduce,    dim3(128),    dim3(256), 0, stream, cPart, c_out);
  } else {
    // fallback: round-2 layout: Bt | attT | bias | ePart | cPart
    u16*   Bt    = (u16*)  (ws);
    float* attT  = (float*)(ws + 1081344);
    float* bias  = (float*)(ws + 1081344 + 8388608);
    float* ePart = (float*)(ws + 1081344 + 8388608 + 65536);
    float* cPart = (float*)(ws + 1081344 + 8388608 + 65536 + 1048576);

    hipLaunchKernelGGL(k_build_bt,      dim3(33,16),  dim3(256), 0, stream, W_enc, W_att, Bt);
    hipLaunchKernelGGL(k_bias,          dim3(8,32),   dim3(256), 0, stream, dec_z, W_dec, b_enc, bias);
    hipLaunchKernelGGL(k_conv_f,        dim3(8192),   dim3(256), 0, stream, att_p, conv_w, attT);
    hipLaunchKernelGGL(k_gemm_energy_f, dim3(2048),   dim3(256), 0, stream, enc, attT, Bt, bias, W_g, ePart);
    hipLaunchKernelGGL(k_softmax,       dim3(32),     dim3(256), 0, stream, ePart, lens, w_out);
    hipLaunchKernelGGL(k_ctx_partial,   dim3(4,8,32), dim3(256), 0, stream, enc, w_out, cPart);
    hipLaunchKernelGGL(k_ctx_reduce,    dim3(128),    dim3(256), 0, stream, cPart, c_out);
  }
}